// Round 12
// baseline (377.703 us; speedup 1.0000x reference)
//
#include <hip/hip_runtime.h>

#define THREADS 256
#define SLAB    64    // per-node capacity; Poisson(16): P(deg>64) ~ 2e-13 whole-graph

typedef float v4f __attribute__((ext_vector_type(4)));

// ---------------- single-pass slab scatter (4B entries => 25.6MB region < L2) -----
// R11 lesson: 8B pairs -> 51.2MB slab region > 32MB aggregate L2 -> lines evicted
// part-filled -> 8x write amplification (99.4MB for 12.8MB payload, 135us). Storing
// only e (4B) halves the region to 25.6MB -> lines stay L2-resident across the pass
// -> writes merge. src is re-derived in agg via esrc[e] (6.4MB, L2-resident; R2-proven).

__global__ __launch_bounds__(THREADS) void k_scatfix2(const int* __restrict__ tgt_row,
                                                      int* __restrict__ cnt,
                                                      int* __restrict__ col,
                                                      int E) {
    int e = blockIdx.x * THREADS + threadIdx.x;
    if (e >= E) return;
    const int tgt = tgt_row[e];
    const int rank = atomicAdd(&cnt[tgt], 1);
    if (rank < SLAB) col[(size_t)tgt * SLAB + rank] = e;
}

// ---------------- aggregation: one WAVE per node, 64 lanes = 8 edges x 8 channels ----
// agg11 body (R9-proven compute + pipeline discipline) with a 3-stage index chain:
//   slab e  : fetched 3 groups ahead (dense per-node slab front, line-aligned)
//   esrc[e] : fetched 2 groups ahead (6.4MB L2-resident gather)
//   operands: fetched 1 group ahead (sh0/sh1/sh2 random, L3-absorbed; node row 128B)
// Every stage has >= one full compute iteration of latency cover.

#define ACC_STRIDE 15   // 14 used +1 pad to break LDS bank conflicts

__global__ __launch_bounds__(THREADS) void k_agg12(const float* __restrict__ node,   // [N][32]
                                                   const int*   __restrict__ cnt,    // per-node count
                                                   const int*   __restrict__ col,    // slabbed e
                                                   const int*   __restrict__ esrc,   // eidx row 0
                                                   const float* __restrict__ sh0,
                                                   const float* __restrict__ sh1,
                                                   const float* __restrict__ sh2,
                                                   const float* __restrict__ W,
                                                   float*       __restrict__ out,
                                                   int N) {
    __shared__ float sW[384];
    __shared__ float sAcc[32 * 8 * ACC_STRIDE];
    for (int t = threadIdx.x; t < 384; t += THREADS) sW[t] = W[t];
    __syncthreads();

    constexpr float IS3  = 0.57735026918962576f;
    constexpr float IS6  = 0.40824829046386302f;
    constexpr float IS10 = 0.31622776601683794f;
    constexpr float IS30 = 0.18257418583505536f;

    const int lane  = threadIdx.x & 63;
    const int wv    = threadIdx.x >> 6;    // wave 0..3
    const int i     = lane & 7;            // channel
    const int jslot = lane >> 3;           // edge slot 0..7

    for (int t = 0; t < 8; ++t) {
        const int n = blockIdx.x * 32 + wv * 8 + t;   // wave-uniform

        float a[14];
        #pragma unroll
        for (int k = 0; k < 14; ++k) a[k] = 0.f;

        if (n < N) {
            int c = cnt[n];
            c = (c < SLAB) ? c : SLAB;     // graceful clamp

            if (c > 0) {
                const int* slab = col + (size_t)n * SLAB;

                // ---- prologue ----
                // group 0: e, src, operands all resolved
                int j0  = jslot;
                int jc0 = (j0 < c) ? j0 : c - 1;
                float mcur = (j0 < c) ? 1.f : 0.f;
                int e0 = slab[jc0];
                int s0 = esrc[e0];
                float s  = sh0[e0];
                const float* up = sh1 + 3*(size_t)e0;
                float u0 = up[0], u1 = up[1], u2 = up[2];
                const float* qp = sh2 + 5*(size_t)e0;
                float q0 = qp[0], q1 = qp[1], q2 = qp[2], q3 = qp[3], q4 = qp[4];
                const float* nr = node + (size_t)s0 * 32;
                float f0 = nr[i];
                float x  = nr[8 + 3*i + 0];
                float y  = nr[8 + 3*i + 1];
                float z  = nr[8 + 3*i + 2];
                // group 1: e + src issued
                int j1  = 8 + jslot;
                int jc1 = (j1 < c) ? j1 : c - 1;
                int eN = slab[jc1];
                int sN = esrc[eN];
                // group 2: e issued
                int j2  = 16 + jslot;
                int jc2 = (j2 < c) ? j2 : c - 1;
                int e2 = slab[jc2];

                for (int g0 = 0; g0 < c; g0 += 8) {
                    const int gn = g0 + 8;
                    const bool more = gn < c;      // wave-uniform
                    float ns = 0.f, nu0 = 0.f, nu1 = 0.f, nu2 = 0.f;
                    float nq0 = 0.f, nq1 = 0.f, nq2 = 0.f, nq3 = 0.f, nq4 = 0.f;
                    float nf0 = 0.f, nx = 0.f, ny = 0.f, nz = 0.f;
                    float mnext = 0.f;
                    int s2 = sN, e3 = e2;
                    if (more) {
                        // operands for group g+1 (e,src resolved >= 1 iter ago)
                        mnext = (gn + jslot < c) ? 1.f : 0.f;
                        ns = sh0[eN];
                        const float* nup = sh1 + 3*(size_t)eN;
                        nu0 = nup[0]; nu1 = nup[1]; nu2 = nup[2];
                        const float* nqp = sh2 + 5*(size_t)eN;
                        nq0 = nqp[0]; nq1 = nqp[1]; nq2 = nqp[2]; nq3 = nqp[3]; nq4 = nqp[4];
                        const float* nrn = node + (size_t)sN * 32;
                        nf0 = nrn[i];
                        nx  = nrn[8 + 3*i + 0];
                        ny  = nrn[8 + 3*i + 1];
                        nz  = nrn[8 + 3*i + 2];
                        // src for group g+2 (e arrived last iter)
                        s2 = esrc[e2];
                        // e for group g+3
                        int j3  = gn + 16 + jslot;
                        int jc3 = (j3 < c) ? j3 : c - 1;
                        e3 = slab[jc3];
                    }

                    // ---- compute group g (operands loaded >= 1 iteration ago) ----
                    const float mf0 = f0 * mcur;
                    const float mx  = x  * mcur;
                    const float my  = y  * mcur;
                    const float mz  = z  * mcur;

                    const float Q00 = -q2*IS30 - q4*IS10;
                    const float Q01 =  q1*IS10;
                    const float Q02 =  q0*IS10;
                    const float Q11 =  2.0f*q2*IS30;
                    const float Q12 =  q3*IS10;
                    const float Q22 = -q2*IS30 + q4*IS10;

                    a[0]  += s * mf0;
                    a[1]  += u0*mx + u1*my + u2*mz;
                    a[2]  += s * mx;
                    a[3]  += s * my;
                    a[4]  += s * mz;
                    a[5]  += mf0 * u0;
                    a[6]  += mf0 * u1;
                    a[7]  += mf0 * u2;
                    a[8]  += u1*mz - u2*my;
                    a[9]  += u2*mx - u0*mz;
                    a[10] += u0*my - u1*mx;
                    a[11] += Q00*mx + Q01*my + Q02*mz;
                    a[12] += Q01*mx + Q11*my + Q12*mz;
                    a[13] += Q02*mx + Q12*my + Q22*mz;

                    // rotate pipeline
                    if (more) {
                        s = ns; u0 = nu0; u1 = nu1; u2 = nu2;
                        q0 = nq0; q1 = nq1; q2 = nq2; q3 = nq3; q4 = nq4;
                        f0 = nf0; x = nx; y = ny; z = nz;
                        eN = e2; sN = s2; e2 = e3; mcur = mnext;
                    }
                }
            }
        }

        // reduce across the 8 edge slots (lane bits 3..5); no divergence
        #pragma unroll
        for (int k = 0; k < 14; ++k) {
            float v = a[k];
            v += __shfl_xor(v, 8);
            v += __shfl_xor(v, 16);
            v += __shfl_xor(v, 32);
            a[k] = v;
        }

        if (n < N && jslot == 0) {
            #pragma unroll
            for (int k = 1; k < 8; ++k) a[k] *= IS3;
            #pragma unroll
            for (int k = 8; k < 11; ++k) a[k] *= IS6;
            float* myAcc = &sAcc[((wv * 8 + t) * 8 + i) * ACC_STRIDE];
            #pragma unroll
            for (int k = 0; k < 14; ++k) myAcc[k] = a[k];
        }
    }
    __syncthreads();

    // per-node postmix (channel-mixing weights), 8 threads per node  [R8/R9-proven]
    {
        const int nodeSlot = threadIdx.x >> 3;
        const int o        = threadIdx.x & 7;
        const int n        = blockIdx.x * 32 + nodeSlot;
        if (n < N) {
            float o0 = 0.f, ox = 0.f, oy = 0.f, oz = 0.f;
            #pragma unroll
            for (int ii = 0; ii < 8; ++ii) {
                const float* A = &sAcc[(nodeSlot * 8 + ii) * ACC_STRIDE];
                const float w0 = sW[  0 + ii*8 + o];
                const float w1 = sW[ 64 + ii*8 + o];
                const float w2 = sW[128 + ii*8 + o];
                const float w3 = sW[192 + ii*8 + o];
                const float w4 = sW[256 + ii*8 + o];
                const float w5 = sW[320 + ii*8 + o];
                o0 += w0*A[0]  + w3*A[1];
                ox += w1*A[2]  + w2*A[5] + w4*A[8]  + w5*A[11];
                oy += w1*A[3]  + w2*A[6] + w4*A[9]  + w5*A[12];
                oz += w1*A[4]  + w2*A[7] + w4*A[10] + w5*A[13];
            }
            float* orow = out + (size_t)n * 32;
            orow[o]         = o0;
            orow[8 + 3*o+0] = ox;
            orow[8 + 3*o+1] = oy;
            orow[8 + 3*o+2] = oz;
        }
    }
}

// ---------------- fallback: atomic kernel (ws-free) ----------------

__global__ __launch_bounds__(THREADS) void msg_kernel_atomic(
    const float* __restrict__ node,
    const int*   __restrict__ eidx,
    const float* __restrict__ sh0,
    const float* __restrict__ sh1,
    const float* __restrict__ sh2,
    const float* __restrict__ W,
    float*       __restrict__ out,
    int E)
{
    __shared__ float sW[384];
    for (int t = threadIdx.x; t < 384; t += THREADS) sW[t] = W[t];
    __syncthreads();

    int e = blockIdx.x * THREADS + threadIdx.x;
    if (e >= E) return;

    constexpr float IS3  = 0.57735026918962576f;
    constexpr float IS6  = 0.40824829046386302f;
    constexpr float IS10 = 0.31622776601683794f;
    constexpr float IS30 = 0.18257418583505536f;

    const int src = eidx[e];
    const int tgt = eidx[E + e];

    const float s  = sh0[e];
    const float u0 = sh1[3*e+0], u1 = sh1[3*e+1], u2 = sh1[3*e+2];
    const float q0 = sh2[5*e+0], q1 = sh2[5*e+1], q2 = sh2[5*e+2],
                q3 = sh2[5*e+3], q4 = sh2[5*e+4];

    const float Q00 = -q2*IS30 - q4*IS10;
    const float Q01 =  q1*IS10;
    const float Q02 =  q0*IS10;
    const float Q11 =  2.0f*q2*IS30;
    const float Q12 =  q3*IS10;
    const float Q22 = -q2*IS30 + q4*IS10;

    float f[32];
    {
        const float4* nr = (const float4*)(node + (size_t)src * 32);
        #pragma unroll
        for (int i = 0; i < 8; ++i) {
            float4 v = nr[i];
            f[4*i+0]=v.x; f[4*i+1]=v.y; f[4*i+2]=v.z; f[4*i+3]=v.w;
        }
    }

    float msg[32];
    #pragma unroll
    for (int j = 0; j < 32; ++j) msg[j] = 0.0f;

    const float s13 = s * IS3;

    #pragma unroll
    for (int i = 0; i < 8; ++i) {
        const float f0i = f[i];
        const float x = f[8+3*i+0], y = f[8+3*i+1], z = f[8+3*i+2];
        const float c0  = s * f0i;
        const float c3  = IS3 * (u0*x + u1*y + u2*z);
        const float p2  = IS3 * f0i;
        const float c1x = s13*x, c1y = s13*y, c1z = s13*z;
        const float c2x = p2*u0, c2y = p2*u1, c2z = p2*u2;
        const float c4x = IS6*(u1*z - u2*y);
        const float c4y = IS6*(u2*x - u0*z);
        const float c4z = IS6*(u0*y - u1*x);
        const float c5x = Q00*x + Q01*y + Q02*z;
        const float c5y = Q01*x + Q11*y + Q12*z;
        const float c5z = Q02*x + Q12*y + Q22*z;

        float wr[6][8];
        #pragma unroll
        for (int c = 0; c < 6; ++c) {
            float4 aa = *(const float4*)&sW[c*64 + i*8 + 0];
            float4 bb = *(const float4*)&sW[c*64 + i*8 + 4];
            wr[c][0]=aa.x; wr[c][1]=aa.y; wr[c][2]=aa.z; wr[c][3]=aa.w;
            wr[c][4]=bb.x; wr[c][5]=bb.y; wr[c][6]=bb.z; wr[c][7]=bb.w;
        }

        #pragma unroll
        for (int o = 0; o < 8; ++o) {
            msg[o] += wr[0][o]*c0 + wr[3][o]*c3;
            msg[8+3*o+0] += wr[1][o]*c1x + wr[2][o]*c2x + wr[4][o]*c4x + wr[5][o]*c5x;
            msg[8+3*o+1] += wr[1][o]*c1y + wr[2][o]*c2y + wr[4][o]*c4y + wr[5][o]*c5y;
            msg[8+3*o+2] += wr[1][o]*c1z + wr[2][o]*c2z + wr[4][o]*c4z + wr[5][o]*c5z;
        }
    }

    float* orow = out + (size_t)tgt * 32;
    #pragma unroll
    for (int j = 0; j < 32; ++j) unsafeAtomicAdd(orow + j, msg[j]);
}

// ---------------- host ----------------

extern "C" void kernel_launch(void* const* d_in, const int* in_sizes, int n_in,
                              void* d_out, int out_size, void* d_ws, size_t ws_size,
                              hipStream_t stream) {
    const float* node = (const float*)d_in[0];
    const int*   eidx = (const int*)d_in[1];
    const float* sh0  = (const float*)d_in[2];
    const float* sh1  = (const float*)d_in[3];
    const float* sh2  = (const float*)d_in[4];
    const float* W    = (const float*)d_in[5];
    float* out = (float*)d_out;

    const int E = in_sizes[2];          // sh0 has E elements
    const int N = in_sizes[0] / 32;     // node_irreps is [N, 32]

    // ws layout (ints): cnt[N] | col[N*SLAB]
    size_t off_cnt = 0;
    size_t off_col = (size_t)N;
    size_t need = (off_col + (size_t)N * SLAB) * sizeof(int);

    const int gridE = (E + THREADS - 1) / THREADS;

    if (ws_size >= need) {
        int* wsI = (int*)d_ws;
        int* cnt = wsI + off_cnt;
        int* col = wsI + off_col;

        hipMemsetAsync(cnt, 0, (size_t)N * sizeof(int), stream);

        k_scatfix2<<<gridE, THREADS, 0, stream>>>(eidx + E, cnt, col, E);

        k_agg12<<<(N + 31) / 32, THREADS, 0, stream>>>(node, cnt, col, eidx,
                                                       sh0, sh1, sh2, W, out, N);
    } else {
        hipMemsetAsync(d_out, 0, (size_t)out_size * sizeof(float), stream);
        msg_kernel_atomic<<<gridE, THREADS, 0, stream>>>(
            node, eidx, sh0, sh1, sh2, W, out, E);
    }
}

// Round 14
// 344.555 us; speedup vs baseline: 1.0962x; 1.0962x over previous
//
#include <hip/hip_runtime.h>

#define THREADS 256
#define SLAB    32     // slab region = N*32*8B = 25.6MB -> 3.2MB/XCD L2 slice: resident
#define OVF_CAP 8192   // Poisson(16): P(deg>32)~1.3e-4 -> ~13 nodes, ~25 edges expected

typedef float v4f __attribute__((ext_vector_type(4)));
typedef int   v2i __attribute__((ext_vector_type(2)));

// ---------------- single-pass slab scatter with overflow list ----------------
// R11/R12 joint lesson: random small writes merge in L2 only if the destination
// region's per-XCD slice fits L2 for the pass (12.8MB dense: yes; 51.2MB slab: no,
// 8x amplification; 25.6MB slab: 3.2MB/XCD -> yes). 8B (e,src) pairs avoid R12's
// esrc re-gather (+92MB fetch). rank>=SLAB edges (~25/graph) -> (tgt,e) overflow list.

__global__ __launch_bounds__(THREADS) void k_scatfix3(const int* __restrict__ eidx,
                                                      int* __restrict__ cnt,
                                                      int* __restrict__ ovf_cnt,
                                                      int* __restrict__ ovf,
                                                      int* __restrict__ col2,
                                                      int E) {
    int e = blockIdx.x * THREADS + threadIdx.x;
    if (e >= E) return;
    const int src = eidx[e];
    const int tgt = eidx[E + e];
    const int rank = atomicAdd(&cnt[tgt], 1);
    if (rank < SLAB) {
        v2i v; v[0] = e; v[1] = src;
        *(v2i*)(col2 + 2 * ((size_t)tgt * SLAB + rank)) = v;
    } else {
        int k = atomicAdd(ovf_cnt, 1);
        if (k < OVF_CAP) { ovf[2*k] = tgt; ovf[2*k+1] = e; }
    }
}

// ---------------- aggregation: one WAVE per node, 64 lanes = 8 edges x 8 channels ----
// R11's k_agg11 body verbatim (133.5us / 399MB proven) with SLAB=32 + overflow merge:
// nodes with cnt>SLAB scan the tiny L2-hot overflow list before the shfl reduce;
// matching edges accumulate on jslot==0 lanes (reduce then counts them once).

#define ACC_STRIDE 15   // 14 used +1 pad to break LDS bank conflicts

__global__ __launch_bounds__(THREADS) void k_agg13(const float* __restrict__ node,   // [N][32]
                                                   const int*   __restrict__ cnt,
                                                   const int*   __restrict__ col2,   // slabbed (e,src)
                                                   const int*   __restrict__ ovf_cnt,
                                                   const int*   __restrict__ ovf,    // (tgt,e) pairs
                                                   const int*   __restrict__ esrc,   // eidx row 0
                                                   const float* __restrict__ sh0,
                                                   const float* __restrict__ sh1,
                                                   const float* __restrict__ sh2,
                                                   const float* __restrict__ W,
                                                   float*       __restrict__ out,
                                                   int N) {
    __shared__ float sW[384];
    __shared__ float sAcc[32 * 8 * ACC_STRIDE];
    for (int t = threadIdx.x; t < 384; t += THREADS) sW[t] = W[t];
    __syncthreads();

    constexpr float IS3  = 0.57735026918962576f;
    constexpr float IS6  = 0.40824829046386302f;
    constexpr float IS10 = 0.31622776601683794f;
    constexpr float IS30 = 0.18257418583505536f;

    const int lane  = threadIdx.x & 63;
    const int wv    = threadIdx.x >> 6;    // wave 0..3
    const int i     = lane & 7;            // channel
    const int jslot = lane >> 3;           // edge slot 0..7

    const int ovfK0 = ovf_cnt[0];
    const int ovfK  = (ovfK0 < OVF_CAP) ? ovfK0 : OVF_CAP;

    for (int t = 0; t < 8; ++t) {
        const int n = blockIdx.x * 32 + wv * 8 + t;   // wave-uniform

        float a[14];
        #pragma unroll
        for (int k = 0; k < 14; ++k) a[k] = 0.f;

        if (n < N) {
            const int craw = cnt[n];
            const int c = (craw < SLAB) ? craw : SLAB;

            if (c > 0) {
                const int* slab = col2 + 2 * ((size_t)n * SLAB);

                // ---- prologue ----
                int j0  = jslot;
                int jc0 = (j0 < c) ? j0 : c - 1;
                float mcur = (j0 < c) ? 1.f : 0.f;
                v2i ec = *(const v2i*)(slab + 2 * jc0);
                float s  = sh0[ec[0]];
                const float* up = sh1 + 3*(size_t)ec[0];
                float u0 = up[0], u1 = up[1], u2 = up[2];
                const float* qp = sh2 + 5*(size_t)ec[0];
                float q0 = qp[0], q1 = qp[1], q2 = qp[2], q3 = qp[3], q4 = qp[4];
                const float* nr = node + (size_t)ec[1] * 32;
                float f0 = nr[i];
                float x  = nr[8 + 3*i + 0];
                float y  = nr[8 + 3*i + 1];
                float z  = nr[8 + 3*i + 2];
                // group 1 pair
                int j1  = 8 + jslot;
                int jc1 = (j1 < c) ? j1 : c - 1;
                v2i ecn = *(const v2i*)(slab + 2 * jc1);

                for (int g0 = 0; g0 < c; g0 += 8) {
                    const int gn = g0 + 8;
                    const bool more = gn < c;      // wave-uniform
                    float ns = 0.f, nu0 = 0.f, nu1 = 0.f, nu2 = 0.f;
                    float nq0 = 0.f, nq1 = 0.f, nq2 = 0.f, nq3 = 0.f, nq4 = 0.f;
                    float nf0 = 0.f, nx = 0.f, ny = 0.f, nz = 0.f;
                    float mnext = 0.f;
                    v2i ec2 = ecn;
                    if (more) {
                        mnext = (gn + jslot < c) ? 1.f : 0.f;
                        ns = sh0[ecn[0]];
                        const float* nup = sh1 + 3*(size_t)ecn[0];
                        nu0 = nup[0]; nu1 = nup[1]; nu2 = nup[2];
                        const float* nqp = sh2 + 5*(size_t)ecn[0];
                        nq0 = nqp[0]; nq1 = nqp[1]; nq2 = nqp[2]; nq3 = nqp[3]; nq4 = nqp[4];
                        const float* nrn = node + (size_t)ecn[1] * 32;
                        nf0 = nrn[i];
                        nx  = nrn[8 + 3*i + 0];
                        ny  = nrn[8 + 3*i + 1];
                        nz  = nrn[8 + 3*i + 2];
                        // pair for group g+2
                        int j2  = gn + 8 + jslot;
                        int jc2 = (j2 < c) ? j2 : c - 1;
                        ec2 = *(const v2i*)(slab + 2 * jc2);
                    }

                    // ---- compute group g ----
                    const float mf0 = f0 * mcur;
                    const float mx  = x  * mcur;
                    const float my  = y  * mcur;
                    const float mz  = z  * mcur;

                    const float Q00 = -q2*IS30 - q4*IS10;
                    const float Q01 =  q1*IS10;
                    const float Q02 =  q0*IS10;
                    const float Q11 =  2.0f*q2*IS30;
                    const float Q12 =  q3*IS10;
                    const float Q22 = -q2*IS30 + q4*IS10;

                    a[0]  += s * mf0;
                    a[1]  += u0*mx + u1*my + u2*mz;
                    a[2]  += s * mx;
                    a[3]  += s * my;
                    a[4]  += s * mz;
                    a[5]  += mf0 * u0;
                    a[6]  += mf0 * u1;
                    a[7]  += mf0 * u2;
                    a[8]  += u1*mz - u2*my;
                    a[9]  += u2*mx - u0*mz;
                    a[10] += u0*my - u1*mx;
                    a[11] += Q00*mx + Q01*my + Q02*mz;
                    a[12] += Q01*mx + Q11*my + Q12*mz;
                    a[13] += Q02*mx + Q12*my + Q22*mz;

                    // rotate pipeline
                    if (more) {
                        s = ns; u0 = nu0; u1 = nu1; u2 = nu2;
                        q0 = nq0; q1 = nq1; q2 = nq2; q3 = nq3; q4 = nq4;
                        f0 = nf0; x = nx; y = ny; z = nz;
                        ecn = ec2; mcur = mnext;
                    }
                }
            }

            // ---- overflow merge (rare: ~13 nodes/graph; list L2-hot, ~25 entries) ----
            if (craw > SLAB) {
                for (int k = 0; k < ovfK; ++k) {
                    const int ot = ovf[2*k];
                    if (ot == n && jslot == 0) {
                        const int oe  = ovf[2*k+1];
                        const int osr = esrc[oe];
                        const float s_  = sh0[oe];
                        const float* up_ = sh1 + 3*(size_t)oe;
                        const float u0_ = up_[0], u1_ = up_[1], u2_ = up_[2];
                        const float* qp_ = sh2 + 5*(size_t)oe;
                        const float q0_ = qp_[0], q1_ = qp_[1], q2_ = qp_[2],
                                    q3_ = qp_[3], q4_ = qp_[4];
                        const float* nr_ = node + (size_t)osr * 32;
                        const float f0_ = nr_[i];
                        const float x_  = nr_[8 + 3*i + 0];
                        const float y_  = nr_[8 + 3*i + 1];
                        const float z_  = nr_[8 + 3*i + 2];

                        const float Q00 = -q2_*IS30 - q4_*IS10;
                        const float Q01 =  q1_*IS10;
                        const float Q02 =  q0_*IS10;
                        const float Q11 =  2.0f*q2_*IS30;
                        const float Q12 =  q3_*IS10;
                        const float Q22 = -q2_*IS30 + q4_*IS10;

                        a[0]  += s_ * f0_;
                        a[1]  += u0_*x_ + u1_*y_ + u2_*z_;
                        a[2]  += s_ * x_;
                        a[3]  += s_ * y_;
                        a[4]  += s_ * z_;
                        a[5]  += f0_ * u0_;
                        a[6]  += f0_ * u1_;
                        a[7]  += f0_ * u2_;
                        a[8]  += u1_*z_ - u2_*y_;
                        a[9]  += u2_*x_ - u0_*z_;
                        a[10] += u0_*y_ - u1_*x_;
                        a[11] += Q00*x_ + Q01*y_ + Q02*z_;
                        a[12] += Q01*x_ + Q11*y_ + Q12*z_;
                        a[13] += Q02*x_ + Q12*y_ + Q22*z_;
                    }
                }
            }
        }

        // reduce across the 8 edge slots (lane bits 3..5); no divergence
        #pragma unroll
        for (int k = 0; k < 14; ++k) {
            float v = a[k];
            v += __shfl_xor(v, 8);
            v += __shfl_xor(v, 16);
            v += __shfl_xor(v, 32);
            a[k] = v;
        }

        if (n < N && jslot == 0) {
            #pragma unroll
            for (int k = 1; k < 8; ++k) a[k] *= IS3;
            #pragma unroll
            for (int k = 8; k < 11; ++k) a[k] *= IS6;
            float* myAcc = &sAcc[((wv * 8 + t) * 8 + i) * ACC_STRIDE];
            #pragma unroll
            for (int k = 0; k < 14; ++k) myAcc[k] = a[k];
        }
    }
    __syncthreads();

    // per-node postmix (channel-mixing weights), 8 threads per node  [R8/R9-proven]
    {
        const int nodeSlot = threadIdx.x >> 3;
        const int o        = threadIdx.x & 7;
        const int n        = blockIdx.x * 32 + nodeSlot;
        if (n < N) {
            float o0 = 0.f, ox = 0.f, oy = 0.f, oz = 0.f;
            #pragma unroll
            for (int ii = 0; ii < 8; ++ii) {
                const float* A = &sAcc[(nodeSlot * 8 + ii) * ACC_STRIDE];
                const float w0 = sW[  0 + ii*8 + o];
                const float w1 = sW[ 64 + ii*8 + o];
                const float w2 = sW[128 + ii*8 + o];
                const float w3 = sW[192 + ii*8 + o];
                const float w4 = sW[256 + ii*8 + o];
                const float w5 = sW[320 + ii*8 + o];
                o0 += w0*A[0]  + w3*A[1];
                ox += w1*A[2]  + w2*A[5] + w4*A[8]  + w5*A[11];
                oy += w1*A[3]  + w2*A[6] + w4*A[9]  + w5*A[12];
                oz += w1*A[4]  + w2*A[7] + w4*A[10] + w5*A[13];
            }
            float* orow = out + (size_t)n * 32;
            orow[o]         = o0;
            orow[8 + 3*o+0] = ox;
            orow[8 + 3*o+1] = oy;
            orow[8 + 3*o+2] = oz;
        }
    }
}

// ---------------- fallback: atomic kernel (ws-free) ----------------

__global__ __launch_bounds__(THREADS) void msg_kernel_atomic(
    const float* __restrict__ node,
    const int*   __restrict__ eidx,
    const float* __restrict__ sh0,
    const float* __restrict__ sh1,
    const float* __restrict__ sh2,
    const float* __restrict__ W,
    float*       __restrict__ out,
    int E)
{
    __shared__ float sW[384];
    for (int t = threadIdx.x; t < 384; t += THREADS) sW[t] = W[t];
    __syncthreads();

    int e = blockIdx.x * THREADS + threadIdx.x;
    if (e >= E) return;

    constexpr float IS3  = 0.57735026918962576f;
    constexpr float IS6  = 0.40824829046386302f;
    constexpr float IS10 = 0.31622776601683794f;
    constexpr float IS30 = 0.18257418583505536f;

    const int src = eidx[e];
    const int tgt = eidx[E + e];

    const float s  = sh0[e];
    const float u0 = sh1[3*e+0], u1 = sh1[3*e+1], u2 = sh1[3*e+2];
    const float q0 = sh2[5*e+0], q1 = sh2[5*e+1], q2 = sh2[5*e+2],
                q3 = sh2[5*e+3], q4 = sh2[5*e+4];

    const float Q00 = -q2*IS30 - q4*IS10;
    const float Q01 =  q1*IS10;
    const float Q02 =  q0*IS10;
    const float Q11 =  2.0f*q2*IS30;
    const float Q12 =  q3*IS10;
    const float Q22 = -q2*IS30 + q4*IS10;

    float f[32];
    {
        const float4* nr = (const float4*)(node + (size_t)src * 32);
        #pragma unroll
        for (int i = 0; i < 8; ++i) {
            float4 v = nr[i];
            f[4*i+0]=v.x; f[4*i+1]=v.y; f[4*i+2]=v.z; f[4*i+3]=v.w;
        }
    }

    float msg[32];
    #pragma unroll
    for (int j = 0; j < 32; ++j) msg[j] = 0.0f;

    const float s13 = s * IS3;

    #pragma unroll
    for (int i = 0; i < 8; ++i) {
        const float f0i = f[i];
        const float x = f[8+3*i+0], y = f[8+3*i+1], z = f[8+3*i+2];
        const float c0  = s * f0i;
        const float c3  = IS3 * (u0*x + u1*y + u2*z);
        const float p2  = IS3 * f0i;
        const float c1x = s13*x, c1y = s13*y, c1z = s13*z;
        const float c2x = p2*u0, c2y = p2*u1, c2z = p2*u2;
        const float c4x = IS6*(u1*z - u2*y);
        const float c4y = IS6*(u2*x - u0*z);
        const float c4z = IS6*(u0*y - u1*x);
        const float c5x = Q00*x + Q01*y + Q02*z;
        const float c5y = Q01*x + Q11*y + Q12*z;
        const float c5z = Q02*x + Q12*y + Q22*z;

        float wr[6][8];
        #pragma unroll
        for (int c = 0; c < 6; ++c) {
            float4 aa = *(const float4*)&sW[c*64 + i*8 + 0];
            float4 bb = *(const float4*)&sW[c*64 + i*8 + 4];
            wr[c][0]=aa.x; wr[c][1]=aa.y; wr[c][2]=aa.z; wr[c][3]=aa.w;
            wr[c][4]=bb.x; wr[c][5]=bb.y; wr[c][6]=bb.z; wr[c][7]=bb.w;
        }

        #pragma unroll
        for (int o = 0; o < 8; ++o) {
            msg[o] += wr[0][o]*c0 + wr[3][o]*c3;
            msg[8+3*o+0] += wr[1][o]*c1x + wr[2][o]*c2x + wr[4][o]*c4x + wr[5][o]*c5x;
            msg[8+3*o+1] += wr[1][o]*c1y + wr[2][o]*c2y + wr[4][o]*c4y + wr[5][o]*c5y;
            msg[8+3*o+2] += wr[1][o]*c1z + wr[2][o]*c2z + wr[4][o]*c4z + wr[5][o]*c5z;
        }
    }

    float* orow = out + (size_t)tgt * 32;
    #pragma unroll
    for (int j = 0; j < 32; ++j) unsafeAtomicAdd(orow + j, msg[j]);
}

// ---------------- host ----------------

extern "C" void kernel_launch(void* const* d_in, const int* in_sizes, int n_in,
                              void* d_out, int out_size, void* d_ws, size_t ws_size,
                              hipStream_t stream) {
    const float* node = (const float*)d_in[0];
    const int*   eidx = (const int*)d_in[1];
    const float* sh0  = (const float*)d_in[2];
    const float* sh1  = (const float*)d_in[3];
    const float* sh2  = (const float*)d_in[4];
    const float* W    = (const float*)d_in[5];
    float* out = (float*)d_out;

    const int E = in_sizes[2];          // sh0 has E elements
    const int N = in_sizes[0] / 32;     // node_irreps is [N, 32]

    // ws layout (ints): cnt[N] | ovf_cnt[1] | ovf[2*OVF_CAP] | (8B align) col2[N*SLAB*2]
    size_t off_cnt    = 0;
    size_t off_ovfcnt = (size_t)N;
    size_t off_ovf    = (size_t)N + 1;
    size_t off_col2   = (off_ovf + 2*(size_t)OVF_CAP + 1) & ~(size_t)1;
    size_t need = (off_col2 + (size_t)N * SLAB * 2) * sizeof(int);

    const int gridE = (E + THREADS - 1) / THREADS;

    if (ws_size >= need) {
        int* wsI     = (int*)d_ws;
        int* cnt     = wsI + off_cnt;
        int* ovf_cnt = wsI + off_ovfcnt;
        int* ovf     = wsI + off_ovf;
        int* col2    = wsI + off_col2;

        // zero cnt + ovf_cnt (contiguous by layout)
        hipMemsetAsync(cnt, 0, (size_t)(N + 1) * sizeof(int), stream);

        k_scatfix3<<<gridE, THREADS, 0, stream>>>(eidx, cnt, ovf_cnt, ovf, col2, E);

        k_agg13<<<(N + 31) / 32, THREADS, 0, stream>>>(node, cnt, col2, ovf_cnt, ovf,
                                                       eidx, sh0, sh1, sh2, W, out, N);
    } else {
        hipMemsetAsync(d_out, 0, (size_t)out_size * sizeof(float), stream);
        msg_kernel_atomic<<<gridE, THREADS, 0, stream>>>(
            node, eidx, sh0, sh1, sh2, W, out, E);
    }
}